// Round 7
// baseline (642.023 us; speedup 1.0000x reference)
//
#include <hip/hip_runtime.h>
#include <hip/hip_bf16.h>
#include <hip/hip_cooperative_groups.h>
#include <math.h>

namespace cg = cooperative_groups;

#define N_NODES 50000
#define N_EDGES 800000

typedef __attribute__((ext_vector_type(8))) short bf16x8;   // 4 VGPRs, MFMA A/B frag
typedef __attribute__((ext_vector_type(4))) float f32x4;    // MFMA C/D frag

__device__ inline unsigned short f2bf(float f) {   // RNE float->bf16
    unsigned u = __float_as_uint(f);
    unsigned r = (u + 0x7fffu + ((u >> 16) & 1u)) >> 16;
    return (unsigned short)r;
}

// packed RNE f32x8 -> bf16x8 (v_cvt_pk_bf16_f32)
__device__ inline bf16x8 pack8(float4 a0, float4 a1) {
    union { __hip_bfloat162 h2[4]; bf16x8 v; } u;
    u.h2[0] = __float22bfloat162_rn(make_float2(a0.x, a0.y));
    u.h2[1] = __float22bfloat162_rn(make_float2(a0.z, a0.w));
    u.h2[2] = __float22bfloat162_rn(make_float2(a1.x, a1.y));
    u.h2[3] = __float22bfloat162_rn(make_float2(a1.z, a1.w));
    return u.v;
}

// ---------------------------------------------------------------------------
// Shared device helper: weight conversion (same indexing as proven
// convert_hist round-0 code, parameterized on linear thread id t).
// ---------------------------------------------------------------------------
__device__ inline void convert_weights_at(
    int t,
    const float* __restrict__ W1, const float* __restrict__ W2,
    const float* __restrict__ We, const float* __restrict__ W3,
    unsigned short* __restrict__ W1frag, unsigned short* __restrict__ W2frag,
    unsigned short* __restrict__ Wcfrag)
{
    if (t < 65536) {                           // W1frag
        int h = t >> 15;
        int r1 = t & 32767;
        int j = r1 >> 13;
        int r2 = r1 & 8191;
        int s = r2 >> 9;
        int r3 = r2 & 511;
        int lane = r3 >> 3, jj = r3 & 7;
        int k = s * 32 + (lane >> 4) * 8 + jj;
        int n = h * 64 + j * 16 + (lane & 15);
        float v = (k < 500) ? W1[k * 128 + n] : 0.0f;
        W1frag[t] = f2bf(v);
    } else if (t < 73728) {                    // W2frag (8192)
        int t2 = t - 65536;
        int j = t2 >> 11;
        int s = (t2 >> 9) & 3;
        int lane = (t2 >> 3) & 63, jj = t2 & 7;
        int k = s * 32 + (lane >> 4) * 8 + jj;
        int n = j * 16 + (lane & 15);
        W2frag[t2] = f2bf(W2[k * 64 + n]);
    } else if (t < 78848) {                    // Wcfrag (5120)
        int t3 = t - 73728;
        int j = t3 >> 10;
        int s = (t3 >> 9) & 1;
        int lane = (t3 >> 3) & 63, jj = t3 & 7;
        int k = s * 32 + (lane >> 4) * 8 + jj;
        int n = j * 16 + (lane & 15);
        float v = (n < 64) ? We[k * 64 + n] : W3[k * 16 + (n - 64)];
        Wcfrag[t3] = f2bf(v);
    }
}

// ---------------------------------------------------------------------------
// COOPERATIVE prep: zero-counts -> (convert || hist) -> scan -> fill, with
// grid.sync() between phases. Replaces 4 dispatches (memset, convert_hist,
// scan, fill) with 1, saving 3 launch gaps + a dispatch. 1024 blocks x 256
// threads, __launch_bounds__(256,4) guarantees 4 blocks/CU co-residency
// (capacity 1024 = grid size).
// ---------------------------------------------------------------------------
__global__ __launch_bounds__(256, 4) void prep_coop_kernel(
    const float* __restrict__ W1, const float* __restrict__ W2,
    const float* __restrict__ We, const float* __restrict__ W3,
    unsigned short* __restrict__ W1frag, unsigned short* __restrict__ W2frag,
    unsigned short* __restrict__ Wcfrag,
    const int* __restrict__ esrc, const int* __restrict__ edst,
    const float* __restrict__ evals,
    int* __restrict__ counts, int* __restrict__ row_ptr,
    int* __restrict__ cursor, int2* __restrict__ pairs)
{
    cg::grid_group grid = cg::this_grid();
    const int NT = gridDim.x * 256;                       // 262144
    const int gtid = blockIdx.x * 256 + threadIdx.x;

    __shared__ int wsum[4];
    __shared__ int carry_s;

    // ---- P0: zero counts ----
    for (int i = gtid; i < N_NODES; i += NT) counts[i] = 0;
    grid.sync();

    // ---- P1: weight conversion + edge histogram ----
    convert_weights_at(gtid, W1, W2, We, W3, W1frag, W2frag, Wcfrag);
    for (int e = gtid; e < N_EDGES; e += NT)
        atomicAdd(&counts[esrc[e]], 1);
    grid.sync();

    // ---- P2: exclusive scan (block 0 only; 256 thr, 4 int4/thread/tile) ----
    if (blockIdx.x == 0) {
        constexpr int Q = N_NODES / 4;          // 12500 int4
        const int t = threadIdx.x;
        const int lane = t & 63, wave = t >> 6; // 4 waves
        int carry = 0;
        const int4* c4 = reinterpret_cast<const int4*>(counts);
        int4* rp4 = reinterpret_cast<int4*>(row_ptr);
        int4* cu4 = reinterpret_cast<int4*>(cursor);

        for (int base = 0; base < Q; base += 1024) {      // 13 tiles
            int4 v[4];
            int ls[5];
            ls[0] = 0;
#pragma unroll
            for (int k = 0; k < 4; ++k) {
                const int g = base + t * 4 + k;
                if (g < Q) v[k] = c4[g];
                else       v[k] = make_int4(0, 0, 0, 0);
                ls[k + 1] = ls[k] + v[k].x + v[k].y + v[k].z + v[k].w;
            }
            const int s = ls[4];

            int incl = s;
#pragma unroll
            for (int off = 1; off < 64; off <<= 1) {
                int n = __shfl_up(incl, off, 64);
                if (lane >= off) incl += n;
            }
            if (lane == 63) wsum[wave] = incl;
            __syncthreads();
            if (t < 4) {
                int w = wsum[t];
                int inc = w;
#pragma unroll
                for (int off = 1; off < 4; off <<= 1) {
                    int n = __shfl_up(inc, off, 64);
                    if (t >= off) inc += n;
                }
                wsum[t] = inc - w;
                if (t == 3) carry_s = inc;
            }
            __syncthreads();
            const int e0 = carry + wsum[wave] + (incl - s);
#pragma unroll
            for (int k = 0; k < 4; ++k) {
                const int g = base + t * 4 + k;
                if (g < Q) {
                    const int b0 = e0 + ls[k];
                    int4 r;
                    r.x = b0;
                    r.y = r.x + v[k].x;
                    r.z = r.y + v[k].y;
                    r.w = r.z + v[k].z;
                    rp4[g] = r;
                    cu4[g] = r;
                }
            }
            carry += carry_s;
            __syncthreads();
        }
        if (t == 0) row_ptr[N_NODES] = carry;
    }
    grid.sync();

    // ---- P3: CSR fill ----
    for (int e = gtid; e < N_EDGES; e += NT) {
        int pos = atomicAdd(&cursor[esrc[e]], 1);
        pairs[pos] = make_int2(edst[e], __float_as_int(evals[e]));
    }
}

// ---------------------------------------------------------------------------
// FALLBACK prep path (proven round-0/2 kernels) if cooperative launch fails.
// ---------------------------------------------------------------------------
__global__ __launch_bounds__(256) void convert_hist_kernel(
    const float* __restrict__ W1, const float* __restrict__ W2,
    const float* __restrict__ We, const float* __restrict__ W3,
    unsigned short* __restrict__ W1frag, unsigned short* __restrict__ W2frag,
    unsigned short* __restrict__ Wcfrag,
    const int* __restrict__ src, int* __restrict__ counts)
{
    if (blockIdx.x < 308) {
        int t = blockIdx.x * 256 + threadIdx.x;
        convert_weights_at(t, W1, W2, We, W3, W1frag, W2frag, Wcfrag);
    } else {
        int e = (blockIdx.x - 308) * 256 + threadIdx.x;
        if (e < N_EDGES) atomicAdd(&counts[src[e]], 1);
    }
}

__global__ __launch_bounds__(1024) void scan_kernel(
    const int* __restrict__ counts, int* __restrict__ row_ptr,
    int* __restrict__ cursor)
{
    constexpr int Q = N_NODES / 4;
    const int t = threadIdx.x;
    const int lane = t & 63, wave = t >> 6;
    __shared__ int wsum[16];
    __shared__ int carry_s;
    int carry = 0;
    const int4* c4 = reinterpret_cast<const int4*>(counts);
    int4* rp4 = reinterpret_cast<int4*>(row_ptr);
    int4* cu4 = reinterpret_cast<int4*>(cursor);

    for (int base = 0; base < Q; base += 4096) {
        int4 v[4];
        int ls[5];
        ls[0] = 0;
#pragma unroll
        for (int k = 0; k < 4; ++k) {
            const int g = base + t * 4 + k;
            if (g < Q) v[k] = c4[g];
            else       v[k] = make_int4(0, 0, 0, 0);
            ls[k + 1] = ls[k] + v[k].x + v[k].y + v[k].z + v[k].w;
        }
        const int s = ls[4];

        int incl = s;
#pragma unroll
        for (int off = 1; off < 64; off <<= 1) {
            int n = __shfl_up(incl, off, 64);
            if (lane >= off) incl += n;
        }
        if (lane == 63) wsum[wave] = incl;
        __syncthreads();
        if (t < 16) {
            int w = wsum[t];
            int inc = w;
#pragma unroll
            for (int off = 1; off < 16; off <<= 1) {
                int n = __shfl_up(inc, off, 64);
                if (t >= off) inc += n;
            }
            wsum[t] = inc - w;
            if (t == 15) carry_s = inc;
        }
        __syncthreads();
        const int e0 = carry + wsum[wave] + (incl - s);
#pragma unroll
        for (int k = 0; k < 4; ++k) {
            const int g = base + t * 4 + k;
            if (g < Q) {
                const int b0 = e0 + ls[k];
                int4 r;
                r.x = b0;
                r.y = r.x + v[k].x;
                r.z = r.y + v[k].y;
                r.w = r.z + v[k].z;
                rp4[g] = r;
                cu4[g] = r;
            }
        }
        carry += carry_s;
        __syncthreads();
    }
    if (t == 0) row_ptr[N_NODES] = carry;
}

__global__ __launch_bounds__(256) void fill_kernel(
    const int* __restrict__ src, const int* __restrict__ dst,
    const float* __restrict__ vals, int* __restrict__ cursor,
    int2* __restrict__ pairs)
{
    int e = blockIdx.x * 256 + threadIdx.x;
    if (e >= N_EDGES) return;
    int pos = atomicAdd(&cursor[src[e]], 1);
    pairs[pos] = make_int2(dst[e], __float_as_int(vals[e]));
}

// ---------------------------------------------------------------------------
// GEMM1: C[M,128] = A[M,500] @ W1, bf16 out. (round-0 exact)
// ---------------------------------------------------------------------------
__global__ __launch_bounds__(256, 2) void gemm1_mfma_kernel(
    const float* __restrict__ A,
    const unsigned short* __restrict__ W1frag,
    unsigned short* __restrict__ C)
{
    __shared__ __align__(16) unsigned short Bs[32768];   // 64 KB

    const int t = threadIdx.x;
    const int h  = blockIdx.x & 1;
    const int br = blockIdx.x >> 1;
    const int lane = t & 63;
    const int wave = t >> 6;
    const int r = lane & 15, q = lane >> 4;

    {
        const uint4* src = reinterpret_cast<const uint4*>(W1frag + h * 32768);
        uint4* dst = reinterpret_cast<uint4*>(Bs);
#pragma unroll
        for (int i = 0; i < 16; ++i)
            dst[t + i * 256] = src[t + i * 256];
    }
    __syncthreads();

    const int col0 = h * 64;

    for (int c = br * 4 + wave; c < 3125; c += 1024) {
        const float* ap = A + (size_t)(c * 16 + r) * 500;

        f32x4 acc[4];
#pragma unroll
        for (int j = 0; j < 4; ++j) acc[j] = {0.f, 0.f, 0.f, 0.f};

#pragma unroll 4
        for (int s = 0; s < 16; ++s) {
            const int kb = s * 32 + q * 8;
            const int k0 = kb < 496 ? kb : 496;
            const int k1 = (kb + 4) < 496 ? (kb + 4) : 496;
            float4 a0 = *reinterpret_cast<const float4*>(ap + k0);
            float4 a1 = *reinterpret_cast<const float4*>(ap + k1);
            bf16x8 af = pack8(a0, a1);
#pragma unroll
            for (int j = 0; j < 4; ++j) {
                bf16x8 b = *reinterpret_cast<const bf16x8*>(
                    &Bs[(size_t)((j * 16 + s) * 64 + lane) * 8]);
                acc[j] = __builtin_amdgcn_mfma_f32_16x16x32_bf16(af, b, acc[j], 0, 0, 0);
            }
        }

#pragma unroll
        for (int reg = 0; reg < 4; ++reg) {
            const int grow = c * 16 + q * 4 + reg;
#pragma unroll
            for (int j = 0; j < 4; ++j)
                C[(size_t)grow * 128 + col0 + j * 16 + r] = f2bf(acc[j][reg]);
        }
    }
}

// ---------------------------------------------------------------------------
// FUSED gather128 + gemm2.  (round-5 proven WIN)
// ---------------------------------------------------------------------------
__global__ __launch_bounds__(256) void gather128_gemm2_kernel(
    const unsigned short* __restrict__ support, const int2* __restrict__ pairs,
    const int* __restrict__ row_ptr, const float* __restrict__ b1,
    const unsigned short* __restrict__ W2frag,
    unsigned short* __restrict__ sup2)
{
    __shared__ __align__(16) unsigned short Bs[8192];        // W2 frags, 16 KB
    __shared__ __align__(16) unsigned short h1s[16 * 136];   // 16 x 272 B (pad)

    const int t = threadIdx.x;
    const int lane = t & 63, wave = t >> 6;
    const int f = lane & 15, e = lane >> 4;

    // stage W2frag -> LDS (coalesced uint4)
    {
        const uint4* src = reinterpret_cast<const uint4*>(W2frag);
        uint4* dst = reinterpret_cast<uint4*>(Bs);
#pragma unroll
        for (int i = 0; i < 4; ++i)
            dst[t + i * 256] = src[t + i * 256];
    }

    const float4 ba = *reinterpret_cast<const float4*>(b1 + f * 8);
    const float4 bb = *reinterpret_cast<const float4*>(b1 + f * 8 + 4);
    const float bias[8] = {ba.x, ba.y, ba.z, ba.w, bb.x, bb.y, bb.z, bb.w};

    const int node0 = blockIdx.x * 16 + wave * 4;

    for (int nn = 0; nn < 4; ++nn) {
        const int node = node0 + nn;
        int i = row_ptr[node] + e;
        const int end = row_ptr[node + 1];

        float acc[8] = {};
        for (; i + 4 < end; i += 8) {
            int2 p0 = pairs[i], p1 = pairs[i + 4];
            float v0 = __int_as_float(p0.y), v1 = __int_as_float(p1.y);
            uint4 r0 = *reinterpret_cast<const uint4*>(support + (size_t)p0.x * 128 + f * 8);
            uint4 r1 = *reinterpret_cast<const uint4*>(support + (size_t)p1.x * 128 + f * 8);
            unsigned w0[4] = {r0.x, r0.y, r0.z, r0.w};
            unsigned w1[4] = {r1.x, r1.y, r1.z, r1.w};
#pragma unroll
            for (int j = 0; j < 4; ++j) {
                acc[2 * j]     += __uint_as_float(w0[j] << 16) * v0;
                acc[2 * j + 1] += __uint_as_float(w0[j] & 0xffff0000u) * v0;
                acc[2 * j]     += __uint_as_float(w1[j] << 16) * v1;
                acc[2 * j + 1] += __uint_as_float(w1[j] & 0xffff0000u) * v1;
            }
        }
        if (i < end) {
            int2 p = pairs[i];
            float v = __int_as_float(p.y);
            uint4 r = *reinterpret_cast<const uint4*>(support + (size_t)p.x * 128 + f * 8);
            unsigned w[4] = {r.x, r.y, r.z, r.w};
#pragma unroll
            for (int j = 0; j < 4; ++j) {
                acc[2 * j]     += __uint_as_float(w[j] << 16) * v;
                acc[2 * j + 1] += __uint_as_float(w[j] & 0xffff0000u) * v;
            }
        }
#pragma unroll
        for (int j = 0; j < 8; ++j) {
            acc[j] += __shfl_xor(acc[j], 16, 64);
            acc[j] += __shfl_xor(acc[j], 32, 64);
        }
        if (e == 0) {
            unsigned short hv[8];
#pragma unroll
            for (int j = 0; j < 8; ++j) {
                float v = acc[j] + bias[j];
                hv[j] = f2bf(v > 0.0f ? v : 0.0f);
            }
            // row = wave*4+nn, feature group f at f*16 bytes (A-frag order)
            *reinterpret_cast<uint4*>(&h1s[(wave * 4 + nn) * 136 + f * 8]) =
                *reinterpret_cast<uint4*>(hv);
        }
    }
    __syncthreads();

    // ---- MFMA phase: wave = output col-block j; rows = block's 16 nodes ----
    f32x4 acc2 = {0.f, 0.f, 0.f, 0.f};
#pragma unroll
    for (int s = 0; s < 4; ++s) {
        bf16x8 af = *reinterpret_cast<const bf16x8*>(&h1s[f * 136 + (s * 4 + e) * 8]);
        bf16x8 b = *reinterpret_cast<const bf16x8*>(
            &Bs[(size_t)((wave * 4 + s) * 64 + lane) * 8]);
        acc2 = __builtin_amdgcn_mfma_f32_16x16x32_bf16(af, b, acc2, 0, 0, 0);
    }
#pragma unroll
    for (int reg = 0; reg < 4; ++reg) {
        const int grow = blockIdx.x * 16 + e * 4 + reg;
        sup2[(size_t)grow * 64 + wave * 16 + f] = f2bf(acc2[reg]);
    }
}

// ---------------------------------------------------------------------------
// FUSED gather64 + gemm3.  (round-6 proven WIN)
// ---------------------------------------------------------------------------
__global__ __launch_bounds__(256) void gather64_gemm3_kernel(
    const unsigned short* __restrict__ support, const int2* __restrict__ pairs,
    const int* __restrict__ row_ptr, const float* __restrict__ b2,
    const unsigned short* __restrict__ Wcfrag, const float* __restrict__ be,
    float* __restrict__ out2, float* __restrict__ sup3)
{
    __shared__ __align__(16) unsigned short Bs[5120];       // Wc frags, 10 KB
    __shared__ __align__(16) unsigned short h2s[16 * 68];   // 16 x 136 B (pad)

    const int t = threadIdx.x;
    const int lane = t & 63, wave = t >> 6;
    const int f = lane & 7, e = lane >> 3;

    // stage Wcfrag -> LDS (coalesced uint4)
    {
        const uint4* src = reinterpret_cast<const uint4*>(Wcfrag);
        uint4* dst = reinterpret_cast<uint4*>(Bs);
#pragma unroll
        for (int i = 0; i < 2; ++i)
            dst[t + i * 256] = src[t + i * 256];
        if (t < 128) dst[512 + t] = src[512 + t];
    }

    const float4 ba = *reinterpret_cast<const float4*>(b2 + f * 8);
    const float4 bb = *reinterpret_cast<const float4*>(b2 + f * 8 + 4);
    const float bias[8] = {ba.x, ba.y, ba.z, ba.w, bb.x, bb.y, bb.z, bb.w};

    const int node0 = blockIdx.x * 16 + wave * 4;

    for (int nn = 0; nn < 4; ++nn) {
        const int node = node0 + nn;
        int i = row_ptr[node] + e;
        const int end = row_ptr[node + 1];

        float acc[8] = {};
        for (; i + 8 < end; i += 16) {
            int2 p0 = pairs[i], p1 = pairs[i + 8];
            float v0 = __int_as_float(p0.y), v1 = __int_as_float(p1.y);
            uint4 r0 = *reinterpret_cast<const uint4*>(support + (size_t)p0.x * 64 + f * 8);
            uint4 r1 = *reinterpret_cast<const uint4*>(support + (size_t)p1.x * 64 + f * 8);
            unsigned w0[4] = {r0.x, r0.y, r0.z, r0.w};
            unsigned w1[4] = {r1.x, r1.y, r1.z, r1.w};
#pragma unroll
            for (int j = 0; j < 4; ++j) {
                acc[2 * j]     += __uint_as_float(w0[j] << 16) * v0;
                acc[2 * j + 1] += __uint_as_float(w0[j] & 0xffff0000u) * v0;
                acc[2 * j]     += __uint_as_float(w1[j] << 16) * v1;
                acc[2 * j + 1] += __uint_as_float(w1[j] & 0xffff0000u) * v1;
            }
        }
        if (i < end) {
            int2 p = pairs[i];
            float v = __int_as_float(p.y);
            uint4 r = *reinterpret_cast<const uint4*>(support + (size_t)p.x * 64 + f * 8);
            unsigned w[4] = {r.x, r.y, r.z, r.w};
#pragma unroll
            for (int j = 0; j < 4; ++j) {
                acc[2 * j]     += __uint_as_float(w[j] << 16) * v;
                acc[2 * j + 1] += __uint_as_float(w[j] & 0xffff0000u) * v;
            }
        }
#pragma unroll
        for (int j = 0; j < 8; ++j) {
            acc[j] += __shfl_xor(acc[j], 8, 64);
            acc[j] += __shfl_xor(acc[j], 16, 64);
            acc[j] += __shfl_xor(acc[j], 32, 64);
        }
        if (e == 0) {
            unsigned short hv[8];
#pragma unroll
            for (int j = 0; j < 8; ++j) {
                float v = acc[j] + bias[j];
                hv[j] = f2bf(v > 0.0f ? v : 0.0f);
            }
            *reinterpret_cast<uint4*>(&h2s[(wave * 4 + nn) * 68 + f * 8]) =
                *reinterpret_cast<uint4*>(hv);
        }
    }
    __syncthreads();

    // ---- MFMA phase ----
    const int r = lane & 15, q = lane >> 4;
    const bf16x8 af0 = *reinterpret_cast<const bf16x8*>(&h2s[r * 68 + q * 8]);
    const bf16x8 af1 = *reinterpret_cast<const bf16x8*>(&h2s[r * 68 + (4 + q) * 8]);

    f32x4 accA = {0.f, 0.f, 0.f, 0.f};
    accA = __builtin_amdgcn_mfma_f32_16x16x32_bf16(
        af0, *reinterpret_cast<const bf16x8*>(&Bs[(size_t)((wave * 2 + 0) * 64 + lane) * 8]),
        accA, 0, 0, 0);
    accA = __builtin_amdgcn_mfma_f32_16x16x32_bf16(
        af1, *reinterpret_cast<const bf16x8*>(&Bs[(size_t)((wave * 2 + 1) * 64 + lane) * 8]),
        accA, 0, 0, 0);
    const float bev = be[wave * 16 + r];
#pragma unroll
    for (int reg = 0; reg < 4; ++reg) {
        const int grow = blockIdx.x * 16 + q * 4 + reg;
        out2[(size_t)grow * 64 + wave * 16 + r] = accA[reg] + bev;
    }

    if (wave == 0) {   // col-block 4 = W3 -> sup3
        f32x4 accB = {0.f, 0.f, 0.f, 0.f};
        accB = __builtin_amdgcn_mfma_f32_16x16x32_bf16(
            af0, *reinterpret_cast<const bf16x8*>(&Bs[(size_t)((4 * 2 + 0) * 64 + lane) * 8]),
            accB, 0, 0, 0);
        accB = __builtin_amdgcn_mfma_f32_16x16x32_bf16(
            af1, *reinterpret_cast<const bf16x8*>(&Bs[(size_t)((4 * 2 + 1) * 64 + lane) * 8]),
            accB, 0, 0, 0);
#pragma unroll
        for (int reg = 0; reg < 4; ++reg) {
            const int grow = blockIdx.x * 16 + q * 4 + reg;
            sup3[(size_t)grow * 16 + r] = accB[reg];
        }
    }
}

// Gather F=16 (fp32) + fused +b3 and log_softmax. (round-0 proven)
__global__ __launch_bounds__(256) void gather16_lsm_kernel(
    const float* __restrict__ sup3, const int2* __restrict__ pairs,
    const int* __restrict__ row_ptr, const float* __restrict__ b3,
    float* __restrict__ out1)
{
    const int node = blockIdx.x * 4 + (threadIdx.x >> 6);
    const int lane = threadIdx.x & 63;
    const int f = lane & 3, e = lane >> 2;
    int i = row_ptr[node] + e;
    const int end = row_ptr[node + 1];

    float4 acc = {0, 0, 0, 0};
    for (; i + 16 < end; i += 32) {
        int2 p0 = pairs[i], p1 = pairs[i + 16];
        float v0 = __int_as_float(p0.y), v1 = __int_as_float(p1.y);
        float4 m0 = *reinterpret_cast<const float4*>(sup3 + (size_t)p0.x * 16 + f * 4);
        float4 m1 = *reinterpret_cast<const float4*>(sup3 + (size_t)p1.x * 16 + f * 4);
        acc.x += m0.x * v0 + m1.x * v1;
        acc.y += m0.y * v0 + m1.y * v1;
        acc.z += m0.z * v0 + m1.z * v1;
        acc.w += m0.w * v0 + m1.w * v1;
    }
    if (i < end) {
        int2 p = pairs[i];
        float v = __int_as_float(p.y);
        float4 m = *reinterpret_cast<const float4*>(sup3 + (size_t)p.x * 16 + f * 4);
        acc.x += m.x * v; acc.y += m.y * v; acc.z += m.z * v; acc.w += m.w * v;
    }
#pragma unroll
    for (int off = 4; off < 64; off <<= 1) {
        acc.x += __shfl_xor(acc.x, off, 64);
        acc.y += __shfl_xor(acc.y, off, 64);
        acc.z += __shfl_xor(acc.z, off, 64);
        acc.w += __shfl_xor(acc.w, off, 64);
    }
    const float4 b = *reinterpret_cast<const float4*>(b3 + f * 4);
    float a0 = acc.x + b.x, a1 = acc.y + b.y, a2 = acc.z + b.z, a3 = acc.w + b.w;
    float mx = fmaxf(fmaxf(a0, a1), fmaxf(a2, a3));
    mx = fmaxf(mx, __shfl_xor(mx, 1, 64));
    mx = fmaxf(mx, __shfl_xor(mx, 2, 64));
    float s = expf(a0 - mx) + expf(a1 - mx) + expf(a2 - mx) + expf(a3 - mx);
    s += __shfl_xor(s, 1, 64);
    s += __shfl_xor(s, 2, 64);
    const float lse = mx + logf(s);
    if (e == 0) {
        float4 o = {a0 - lse, a1 - lse, a2 - lse, a3 - lse};
        *reinterpret_cast<float4*>(out1 + (size_t)node * 16 + f * 4) = o;
    }
}

// ---------------------------------------------------------------------------
extern "C" void kernel_launch(void* const* d_in, const int* in_sizes, int n_in,
                              void* d_out, int out_size, void* d_ws, size_t ws_size,
                              hipStream_t stream)
{
    const float* x         = (const float*)d_in[0];
    const float* edge_vals = (const float*)d_in[1];
    const float* W1 = (const float*)d_in[2];
    const float* b1 = (const float*)d_in[3];
    const float* W2 = (const float*)d_in[4];
    const float* b2 = (const float*)d_in[5];
    const float* W3 = (const float*)d_in[6];
    const float* b3 = (const float*)d_in[7];
    const float* We = (const float*)d_in[8];
    const float* be = (const float*)d_in[9];
    const int* esrc = (const int*)d_in[10];
    const int* edst = (const int*)d_in[11];

    float* out1 = (float*)d_out;                        // [50000,16]
    float* out2 = (float*)d_out + (size_t)N_NODES * 16; // [50000,64]

    char* ws = (char*)d_ws;
    float* bufA    = (float*)(ws);                    // 25,600,000
    float* bufB    = (float*)(ws + 25600000);         // 25,600,000
    float* bufC    = (float*)(ws + 51200000);         //  3,200,000
    int*   counts  = (int*)  (ws + 54400000);         //    200,064
    int*   row_ptr = (int*)  (ws + 54600064);         //    200,064
    int*   cursor  = (int*)  (ws + 54800128);         //    200,064
    int2*  pairs   = (int2*) (ws + 55000192);         //  6,400,000
    // total: 61,400,192 B

    unsigned short* W1frag = (unsigned short*)bufC;                    // 131,072 B
    unsigned short* W2frag = (unsigned short*)((char*)bufC + 131072);  //  16,384 B
    unsigned short* Wcfrag = (unsigned short*)((char*)bufC + 147456);  //  10,240 B

    // Buffer plan (no within-dispatch aliasing):
    //   sup1 [N,128]bf16 = bufA       (gemm1 w -> g128g2 r)
    //   sup2 [N, 64]bf16 = bufB       (g128g2 w -> g64g3 r)
    //   sup3 [N, 16]f32  = bufA       (g64g3 w, sup1 dead -> g16 r)
    unsigned short* sup1bf = (unsigned short*)bufA;
    unsigned short* sup2bf = (unsigned short*)bufB;
    float*          sup3   = bufA;

    const int EB  = (N_EDGES + 255) / 256;  // 3125
    const int GN  = N_NODES / 4;            // 12500 (wave-per-node gather16)
    const int GB  = N_NODES / 16;           // 3125 (16-node fused blocks)

    // --- one-time prep + CSR build: single cooperative kernel ---
    {
        void* args[] = {
            (void*)&W1, (void*)&W2, (void*)&We, (void*)&W3,
            (void*)&W1frag, (void*)&W2frag, (void*)&Wcfrag,
            (void*)&esrc, (void*)&edst, (void*)&edge_vals,
            (void*)&counts, (void*)&row_ptr, (void*)&cursor, (void*)&pairs};
        hipError_t cerr = hipLaunchCooperativeKernel(
            (void*)prep_coop_kernel, dim3(1024), dim3(256), args, 0, stream);
        if (cerr != hipSuccess) {
            // fallback: proven 4-dispatch chain
            hipMemsetAsync(counts, 0, (size_t)N_NODES * 4, stream);
            convert_hist_kernel<<<308 + EB, 256, 0, stream>>>(
                W1, W2, We, W3, W1frag, W2frag, Wcfrag, esrc, counts);
            scan_kernel<<<1, 1024, 0, stream>>>(counts, row_ptr, cursor);
            fill_kernel<<<EB, 256, 0, stream>>>(esrc, edst, edge_vals, cursor, pairs);
        }
    }

    // 1. support1 = x @ W1 (MFMA, LDS-B)             -> bufA [N,128] bf16
    gemm1_mfma_kernel<<<512, 256, 0, stream>>>(x, W1frag, sup1bf);

    // 2+3. sup2 = relu(gather(sup1)+b1) @ W2 (fused) -> bufB [N,64] bf16
    gather128_gemm2_kernel<<<GB, 256, 0, stream>>>(
        sup1bf, pairs, row_ptr, b1, W2frag, sup2bf);

    // 4+5+6. h2 = relu(gather(sup2)+b2); [out2|sup3] = h2 @ [We|W3] (fused)
    gather64_gemm3_kernel<<<GB, 256, 0, stream>>>(
        sup2bf, pairs, row_ptr, b2, Wcfrag, be, out2, sup3);

    // 7+8. out1 = log_softmax(gather(sup3) + b3)     -> d_out head
    gather16_lsm_kernel<<<GN, 256, 0, stream>>>(sup3, pairs, row_ptr, b3, out1);
}

// Round 8
// 344.782 us; speedup vs baseline: 1.8621x; 1.8621x over previous
//
#include <hip/hip_runtime.h>
#include <hip/hip_bf16.h>
#include <math.h>

#define N_NODES 50000
#define N_EDGES 800000

typedef __attribute__((ext_vector_type(8))) short bf16x8;   // 4 VGPRs, MFMA A/B frag
typedef __attribute__((ext_vector_type(4))) float f32x4;    // MFMA C/D frag

__device__ inline unsigned short f2bf(float f) {   // RNE float->bf16
    unsigned u = __float_as_uint(f);
    unsigned r = (u + 0x7fffu + ((u >> 16) & 1u)) >> 16;
    return (unsigned short)r;
}

// packed RNE f32x8 -> bf16x8 (v_cvt_pk_bf16_f32)
__device__ inline bf16x8 pack8(float4 a0, float4 a1) {
    union { __hip_bfloat162 h2[4]; bf16x8 v; } u;
    u.h2[0] = __float22bfloat162_rn(make_float2(a0.x, a0.y));
    u.h2[1] = __float22bfloat162_rn(make_float2(a0.z, a0.w));
    u.h2[2] = __float22bfloat162_rn(make_float2(a1.x, a1.y));
    u.h2[3] = __float22bfloat162_rn(make_float2(a1.z, a1.w));
    return u.v;
}

// ---------------------------------------------------------------------------
// Fused one-time prep + histogram.  (round-0 proven)
// ---------------------------------------------------------------------------
__global__ __launch_bounds__(256) void convert_hist_kernel(
    const float* __restrict__ W1, const float* __restrict__ W2,
    const float* __restrict__ We, const float* __restrict__ W3,
    unsigned short* __restrict__ W1frag, unsigned short* __restrict__ W2frag,
    unsigned short* __restrict__ Wcfrag,
    const int* __restrict__ src, int* __restrict__ counts)
{
    if (blockIdx.x < 308) {
        int t = blockIdx.x * 256 + threadIdx.x;   // 0..78847
        if (t < 65536) {                           // W1frag
            int h = t >> 15;
            int r1 = t & 32767;
            int j = r1 >> 13;
            int r2 = r1 & 8191;
            int s = r2 >> 9;
            int r3 = r2 & 511;
            int lane = r3 >> 3, jj = r3 & 7;
            int k = s * 32 + (lane >> 4) * 8 + jj;
            int n = h * 64 + j * 16 + (lane & 15);
            float v = (k < 500) ? W1[k * 128 + n] : 0.0f;
            W1frag[t] = f2bf(v);
        } else if (t < 73728) {                    // W2frag (8192)
            int t2 = t - 65536;
            int j = t2 >> 11;
            int s = (t2 >> 9) & 3;
            int lane = (t2 >> 3) & 63, jj = t2 & 7;
            int k = s * 32 + (lane >> 4) * 8 + jj;
            int n = j * 16 + (lane & 15);
            W2frag[t2] = f2bf(W2[k * 64 + n]);
        } else {                                   // Wcfrag (5120)
            int t3 = t - 73728;
            int j = t3 >> 10;
            int s = (t3 >> 9) & 1;
            int lane = (t3 >> 3) & 63, jj = t3 & 7;
            int k = s * 32 + (lane >> 4) * 8 + jj;
            int n = j * 16 + (lane & 15);
            float v = (n < 64) ? We[k * 64 + n] : W3[k * 16 + (n - 64)];
            Wcfrag[t3] = f2bf(v);
        }
    } else {
        int e = (blockIdx.x - 308) * 256 + threadIdx.x;
        if (e < N_EDGES) atomicAdd(&counts[src[e]], 1);
    }
}

// Separate fill (round-0 proven; co-run attempts lost 25-150 us).
__global__ __launch_bounds__(256) void fill_kernel(
    const int* __restrict__ src, const int* __restrict__ dst,
    const float* __restrict__ vals, int* __restrict__ cursor,
    int2* __restrict__ pairs)
{
    int e = blockIdx.x * 256 + threadIdx.x;
    if (e >= N_EDGES) return;
    int pos = atomicAdd(&cursor[src[e]], 1);
    pairs[pos] = make_int2(dst[e], __float_as_int(vals[e]));
}

// ---------------------------------------------------------------------------
// GEMM1 + scan co-run.
// Blocks 0..509: gemm1 (255 row-ranges x 2 col-halves, chunk-loop stride
//   1020 so 255 brs cover all 3125 chunks). 510 + 1 = 511 blocks <= 512
//   resident capacity (64 KB LDS -> 2 blocks/CU) -- no straggler wave,
//   which is what killed the R4 fill co-run (576 > 512).
// Block 510: the HW-validated 256-thread exclusive scan (ran correctly
//   inside R7's coop kernel), ~8 us, fully hidden under gemm1's ~45 us.
//   Scan reads counts (prior dispatch) and feeds fill (next dispatch).
// ---------------------------------------------------------------------------
__global__ __launch_bounds__(256, 2) void gemm1_scan_kernel(
    const float* __restrict__ A,
    const unsigned short* __restrict__ W1frag,
    unsigned short* __restrict__ C,
    const int* __restrict__ counts, int* __restrict__ row_ptr,
    int* __restrict__ cursor)
{
    __shared__ __align__(16) unsigned short Bs[32768];   // 64 KB

    if (blockIdx.x == 510) {
        // ---- scan block (256 thr, 4 waves; 13 tiles of 1024 int4) ----
        constexpr int Q = N_NODES / 4;          // 12500 int4
        __shared__ int wsum[4];
        __shared__ int carry_s;
        const int t = threadIdx.x;
        const int lane = t & 63, wave = t >> 6;
        int carry = 0;
        const int4* c4 = reinterpret_cast<const int4*>(counts);
        int4* rp4 = reinterpret_cast<int4*>(row_ptr);
        int4* cu4 = reinterpret_cast<int4*>(cursor);

        for (int base = 0; base < Q; base += 1024) {
            int4 v[4];
            int ls[5];
            ls[0] = 0;
#pragma unroll
            for (int k = 0; k < 4; ++k) {
                const int g = base + t * 4 + k;
                if (g < Q) v[k] = c4[g];
                else       v[k] = make_int4(0, 0, 0, 0);
                ls[k + 1] = ls[k] + v[k].x + v[k].y + v[k].z + v[k].w;
            }
            const int s = ls[4];

            int incl = s;
#pragma unroll
            for (int off = 1; off < 64; off <<= 1) {
                int n = __shfl_up(incl, off, 64);
                if (lane >= off) incl += n;
            }
            if (lane == 63) wsum[wave] = incl;
            __syncthreads();
            if (t < 4) {
                int w = wsum[t];
                int inc = w;
#pragma unroll
                for (int off = 1; off < 4; off <<= 1) {
                    int n = __shfl_up(inc, off, 64);
                    if (t >= off) inc += n;
                }
                wsum[t] = inc - w;
                if (t == 3) carry_s = inc;
            }
            __syncthreads();
            const int e0 = carry + wsum[wave] + (incl - s);
#pragma unroll
            for (int k = 0; k < 4; ++k) {
                const int g = base + t * 4 + k;
                if (g < Q) {
                    const int b0 = e0 + ls[k];
                    int4 r;
                    r.x = b0;
                    r.y = r.x + v[k].x;
                    r.z = r.y + v[k].y;
                    r.w = r.z + v[k].z;
                    rp4[g] = r;
                    cu4[g] = r;
                }
            }
            carry += carry_s;
            __syncthreads();
        }
        if (t == 0) row_ptr[N_NODES] = carry;
        return;
    }

    // ---- gemm1 blocks (gi 0..509) ----
    const int gi = blockIdx.x;
    const int t = threadIdx.x;
    const int h  = gi & 1;
    const int br = gi >> 1;          // 0..254
    const int lane = t & 63;
    const int wave = t >> 6;
    const int r = lane & 15, q = lane >> 4;

    {
        const uint4* src = reinterpret_cast<const uint4*>(W1frag + h * 32768);
        uint4* dst = reinterpret_cast<uint4*>(Bs);
#pragma unroll
        for (int i = 0; i < 16; ++i)
            dst[t + i * 256] = src[t + i * 256];
    }
    __syncthreads();

    const int col0 = h * 64;

    for (int c = br * 4 + wave; c < 3125; c += 1020) {
        const float* ap = A + (size_t)(c * 16 + r) * 500;

        f32x4 acc[4];
#pragma unroll
        for (int j = 0; j < 4; ++j) acc[j] = {0.f, 0.f, 0.f, 0.f};

#pragma unroll 4
        for (int s = 0; s < 16; ++s) {
            const int kb = s * 32 + q * 8;
            const int k0 = kb < 496 ? kb : 496;
            const int k1 = (kb + 4) < 496 ? (kb + 4) : 496;
            float4 a0 = *reinterpret_cast<const float4*>(ap + k0);
            float4 a1 = *reinterpret_cast<const float4*>(ap + k1);
            bf16x8 af = pack8(a0, a1);
#pragma unroll
            for (int j = 0; j < 4; ++j) {
                bf16x8 b = *reinterpret_cast<const bf16x8*>(
                    &Bs[(size_t)((j * 16 + s) * 64 + lane) * 8]);
                acc[j] = __builtin_amdgcn_mfma_f32_16x16x32_bf16(af, b, acc[j], 0, 0, 0);
            }
        }

#pragma unroll
        for (int reg = 0; reg < 4; ++reg) {
            const int grow = c * 16 + q * 4 + reg;
#pragma unroll
            for (int j = 0; j < 4; ++j)
                C[(size_t)grow * 128 + col0 + j * 16 + r] = f2bf(acc[j][reg]);
        }
    }
}

// ---------------------------------------------------------------------------
// FUSED gather128 + gemm2.  (round-5 proven WIN)
// ---------------------------------------------------------------------------
__global__ __launch_bounds__(256) void gather128_gemm2_kernel(
    const unsigned short* __restrict__ support, const int2* __restrict__ pairs,
    const int* __restrict__ row_ptr, const float* __restrict__ b1,
    const unsigned short* __restrict__ W2frag,
    unsigned short* __restrict__ sup2)
{
    __shared__ __align__(16) unsigned short Bs[8192];        // W2 frags, 16 KB
    __shared__ __align__(16) unsigned short h1s[16 * 136];   // 16 x 272 B (pad)

    const int t = threadIdx.x;
    const int lane = t & 63, wave = t >> 6;
    const int f = lane & 15, e = lane >> 4;

    // stage W2frag -> LDS (coalesced uint4)
    {
        const uint4* src = reinterpret_cast<const uint4*>(W2frag);
        uint4* dst = reinterpret_cast<uint4*>(Bs);
#pragma unroll
        for (int i = 0; i < 4; ++i)
            dst[t + i * 256] = src[t + i * 256];
    }

    const float4 ba = *reinterpret_cast<const float4*>(b1 + f * 8);
    const float4 bb = *reinterpret_cast<const float4*>(b1 + f * 8 + 4);
    const float bias[8] = {ba.x, ba.y, ba.z, ba.w, bb.x, bb.y, bb.z, bb.w};

    const int node0 = blockIdx.x * 16 + wave * 4;

    for (int nn = 0; nn < 4; ++nn) {
        const int node = node0 + nn;
        int i = row_ptr[node] + e;
        const int end = row_ptr[node + 1];

        float acc[8] = {};
        for (; i + 4 < end; i += 8) {
            int2 p0 = pairs[i], p1 = pairs[i + 4];
            float v0 = __int_as_float(p0.y), v1 = __int_as_float(p1.y);
            uint4 r0 = *reinterpret_cast<const uint4*>(support + (size_t)p0.x * 128 + f * 8);
            uint4 r1 = *reinterpret_cast<const uint4*>(support + (size_t)p1.x * 128 + f * 8);
            unsigned w0[4] = {r0.x, r0.y, r0.z, r0.w};
            unsigned w1[4] = {r1.x, r1.y, r1.z, r1.w};
#pragma unroll
            for (int j = 0; j < 4; ++j) {
                acc[2 * j]     += __uint_as_float(w0[j] << 16) * v0;
                acc[2 * j + 1] += __uint_as_float(w0[j] & 0xffff0000u) * v0;
                acc[2 * j]     += __uint_as_float(w1[j] << 16) * v1;
                acc[2 * j + 1] += __uint_as_float(w1[j] & 0xffff0000u) * v1;
            }
        }
        if (i < end) {
            int2 p = pairs[i];
            float v = __int_as_float(p.y);
            uint4 r = *reinterpret_cast<const uint4*>(support + (size_t)p.x * 128 + f * 8);
            unsigned w[4] = {r.x, r.y, r.z, r.w};
#pragma unroll
            for (int j = 0; j < 4; ++j) {
                acc[2 * j]     += __uint_as_float(w[j] << 16) * v;
                acc[2 * j + 1] += __uint_as_float(w[j] & 0xffff0000u) * v;
            }
        }
#pragma unroll
        for (int j = 0; j < 8; ++j) {
            acc[j] += __shfl_xor(acc[j], 16, 64);
            acc[j] += __shfl_xor(acc[j], 32, 64);
        }
        if (e == 0) {
            unsigned short hv[8];
#pragma unroll
            for (int j = 0; j < 8; ++j) {
                float v = acc[j] + bias[j];
                hv[j] = f2bf(v > 0.0f ? v : 0.0f);
            }
            // row = wave*4+nn, feature group f at f*16 bytes (A-frag order)
            *reinterpret_cast<uint4*>(&h1s[(wave * 4 + nn) * 136 + f * 8]) =
                *reinterpret_cast<uint4*>(hv);
        }
    }
    __syncthreads();

    // ---- MFMA phase: wave = output col-block j; rows = block's 16 nodes ----
    f32x4 acc2 = {0.f, 0.f, 0.f, 0.f};
#pragma unroll
    for (int s = 0; s < 4; ++s) {
        bf16x8 af = *reinterpret_cast<const bf16x8*>(&h1s[f * 136 + (s * 4 + e) * 8]);
        bf16x8 b = *reinterpret_cast<const bf16x8*>(
            &Bs[(size_t)((wave * 4 + s) * 64 + lane) * 8]);
        acc2 = __builtin_amdgcn_mfma_f32_16x16x32_bf16(af, b, acc2, 0, 0, 0);
    }
#pragma unroll
    for (int reg = 0; reg < 4; ++reg) {
        const int grow = blockIdx.x * 16 + e * 4 + reg;
        sup2[(size_t)grow * 64 + wave * 16 + f] = f2bf(acc2[reg]);
    }
}

// ---------------------------------------------------------------------------
// FUSED gather64 + gemm3.  (round-6 proven WIN)
// ---------------------------------------------------------------------------
__global__ __launch_bounds__(256) void gather64_gemm3_kernel(
    const unsigned short* __restrict__ support, const int2* __restrict__ pairs,
    const int* __restrict__ row_ptr, const float* __restrict__ b2,
    const unsigned short* __restrict__ Wcfrag, const float* __restrict__ be,
    float* __restrict__ out2, float* __restrict__ sup3)
{
    __shared__ __align__(16) unsigned short Bs[5120];       // Wc frags, 10 KB
    __shared__ __align__(16) unsigned short h2s[16 * 68];   // 16 x 136 B (pad)

    const int t = threadIdx.x;
    const int lane = t & 63, wave = t >> 6;
    const int f = lane & 7, e = lane >> 3;

    // stage Wcfrag -> LDS (coalesced uint4)
    {
        const uint4* src = reinterpret_cast<const uint4*>(Wcfrag);
        uint4* dst = reinterpret_cast<uint4*>(Bs);
#pragma unroll
        for (int i = 0; i < 2; ++i)
            dst[t + i * 256] = src[t + i * 256];
        if (t < 128) dst[512 + t] = src[512 + t];
    }

    const float4 ba = *reinterpret_cast<const float4*>(b2 + f * 8);
    const float4 bb = *reinterpret_cast<const float4*>(b2 + f * 8 + 4);
    const float bias[8] = {ba.x, ba.y, ba.z, ba.w, bb.x, bb.y, bb.z, bb.w};

    const int node0 = blockIdx.x * 16 + wave * 4;

    for (int nn = 0; nn < 4; ++nn) {
        const int node = node0 + nn;
        int i = row_ptr[node] + e;
        const int end = row_ptr[node + 1];

        float acc[8] = {};
        for (; i + 8 < end; i += 16) {
            int2 p0 = pairs[i], p1 = pairs[i + 8];
            float v0 = __int_as_float(p0.y), v1 = __int_as_float(p1.y);
            uint4 r0 = *reinterpret_cast<const uint4*>(support + (size_t)p0.x * 64 + f * 8);
            uint4 r1 = *reinterpret_cast<const uint4*>(support + (size_t)p1.x * 64 + f * 8);
            unsigned w0[4] = {r0.x, r0.y, r0.z, r0.w};
            unsigned w1[4] = {r1.x, r1.y, r1.z, r1.w};
#pragma unroll
            for (int j = 0; j < 4; ++j) {
                acc[2 * j]     += __uint_as_float(w0[j] << 16) * v0;
                acc[2 * j + 1] += __uint_as_float(w0[j] & 0xffff0000u) * v0;
                acc[2 * j]     += __uint_as_float(w1[j] << 16) * v1;
                acc[2 * j + 1] += __uint_as_float(w1[j] & 0xffff0000u) * v1;
            }
        }
        if (i < end) {
            int2 p = pairs[i];
            float v = __int_as_float(p.y);
            uint4 r = *reinterpret_cast<const uint4*>(support + (size_t)p.x * 64 + f * 8);
            unsigned w[4] = {r.x, r.y, r.z, r.w};
#pragma unroll
            for (int j = 0; j < 4; ++j) {
                acc[2 * j]     += __uint_as_float(w[j] << 16) * v;
                acc[2 * j + 1] += __uint_as_float(w[j] & 0xffff0000u) * v;
            }
        }
#pragma unroll
        for (int j = 0; j < 8; ++j) {
            acc[j] += __shfl_xor(acc[j], 8, 64);
            acc[j] += __shfl_xor(acc[j], 16, 64);
            acc[j] += __shfl_xor(acc[j], 32, 64);
        }
        if (e == 0) {
            unsigned short hv[8];
#pragma unroll
            for (int j = 0; j < 8; ++j) {
                float v = acc[j] + bias[j];
                hv[j] = f2bf(v > 0.0f ? v : 0.0f);
            }
            *reinterpret_cast<uint4*>(&h2s[(wave * 4 + nn) * 68 + f * 8]) =
                *reinterpret_cast<uint4*>(hv);
        }
    }
    __syncthreads();

    // ---- MFMA phase ----
    const int r = lane & 15, q = lane >> 4;
    const bf16x8 af0 = *reinterpret_cast<const bf16x8*>(&h2s[r * 68 + q * 8]);
    const bf16x8 af1 = *reinterpret_cast<const bf16x8*>(&h2s[r * 68 + (4 + q) * 8]);

    f32x4 accA = {0.f, 0.f, 0.f, 0.f};
    accA = __builtin_amdgcn_mfma_f32_16x16x32_bf16(
        af0, *reinterpret_cast<const bf16x8*>(&Bs[(size_t)((wave * 2 + 0) * 64 + lane) * 8]),
        accA, 0, 0, 0);
    accA = __builtin_amdgcn_mfma_f32_16x16x32_bf16(
        af1, *reinterpret_cast<const bf16x8*>(&Bs[(size_t)((wave * 2 + 1) * 64 + lane) * 8]),
        accA, 0, 0, 0);
    const float bev = be[wave * 16 + r];
#pragma unroll
    for (int reg = 0; reg < 4; ++reg) {
        const int grow = blockIdx.x * 16 + q * 4 + reg;
        out2[(size_t)grow * 64 + wave * 16 + r] = accA[reg] + bev;
    }

    if (wave == 0) {   // col-block 4 = W3 -> sup3
        f32x4 accB = {0.f, 0.f, 0.f, 0.f};
        accB = __builtin_amdgcn_mfma_f32_16x16x32_bf16(
            af0, *reinterpret_cast<const bf16x8*>(&Bs[(size_t)((4 * 2 + 0) * 64 + lane) * 8]),
            accB, 0, 0, 0);
        accB = __builtin_amdgcn_mfma_f32_16x16x32_bf16(
            af1, *reinterpret_cast<const bf16x8*>(&Bs[(size_t)((4 * 2 + 1) * 64 + lane) * 8]),
            accB, 0, 0, 0);
#pragma unroll
        for (int reg = 0; reg < 4; ++reg) {
            const int grow = blockIdx.x * 16 + q * 4 + reg;
            sup3[(size_t)grow * 16 + r] = accB[reg];
        }
    }
}

// Gather F=16 (fp32) + fused +b3 and log_softmax. (round-0 proven)
__global__ __launch_bounds__(256) void gather16_lsm_kernel(
    const float* __restrict__ sup3, const int2* __restrict__ pairs,
    const int* __restrict__ row_ptr, const float* __restrict__ b3,
    float* __restrict__ out1)
{
    const int node = blockIdx.x * 4 + (threadIdx.x >> 6);
    const int lane = threadIdx.x & 63;
    const int f = lane & 3, e = lane >> 2;
    int i = row_ptr[node] + e;
    const int end = row_ptr[node + 1];

    float4 acc = {0, 0, 0, 0};
    for (; i + 16 < end; i += 32) {
        int2 p0 = pairs[i], p1 = pairs[i + 16];
        float v0 = __int_as_float(p0.y), v1 = __int_as_float(p1.y);
        float4 m0 = *reinterpret_cast<const float4*>(sup3 + (size_t)p0.x * 16 + f * 4);
        float4 m1 = *reinterpret_cast<const float4*>(sup3 + (size_t)p1.x * 16 + f * 4);
        acc.x += m0.x * v0 + m1.x * v1;
        acc.y += m0.y * v0 + m1.y * v1;
        acc.z += m0.z * v0 + m1.z * v1;
        acc.w += m0.w * v0 + m1.w * v1;
    }
    if (i < end) {
        int2 p = pairs[i];
        float v = __int_as_float(p.y);
        float4 m = *reinterpret_cast<const float4*>(sup3 + (size_t)p.x * 16 + f * 4);
        acc.x += m.x * v; acc.y += m.y * v; acc.z += m.z * v; acc.w += m.w * v;
    }
#pragma unroll
    for (int off = 4; off < 64; off <<= 1) {
        acc.x += __shfl_xor(acc.x, off, 64);
        acc.y += __shfl_xor(acc.y, off, 64);
        acc.z += __shfl_xor(acc.z, off, 64);
        acc.w += __shfl_xor(acc.w, off, 64);
    }
    const float4 b = *reinterpret_cast<const float4*>(b3 + f * 4);
    float a0 = acc.x + b.x, a1 = acc.y + b.y, a2 = acc.z + b.z, a3 = acc.w + b.w;
    float mx = fmaxf(fmaxf(a0, a1), fmaxf(a2, a3));
    mx = fmaxf(mx, __shfl_xor(mx, 1, 64));
    mx = fmaxf(mx, __shfl_xor(mx, 2, 64));
    float s = expf(a0 - mx) + expf(a1 - mx) + expf(a2 - mx) + expf(a3 - mx);
    s += __shfl_xor(s, 1, 64);
    s += __shfl_xor(s, 2, 64);
    const float lse = mx + logf(s);
    if (e == 0) {
        float4 o = {a0 - lse, a1 - lse, a2 - lse, a3 - lse};
        *reinterpret_cast<float4*>(out1 + (size_t)node * 16 + f * 4) = o;
    }
}

// ---------------------------------------------------------------------------
extern "C" void kernel_launch(void* const* d_in, const int* in_sizes, int n_in,
                              void* d_out, int out_size, void* d_ws, size_t ws_size,
                              hipStream_t stream)
{
    const float* x         = (const float*)d_in[0];
    const float* edge_vals = (const float*)d_in[1];
    const float* W1 = (const float*)d_in[2];
    const float* b1 = (const float*)d_in[3];
    const float* W2 = (const float*)d_in[4];
    const float* b2 = (const float*)d_in[5];
    const float* W3 = (const float*)d_in[6];
    const float* b3 = (const float*)d_in[7];
    const float* We = (const float*)d_in[8];
    const float* be = (const float*)d_in[9];
    const int* esrc = (const int*)d_in[10];
    const int* edst = (const int*)d_in[11];

    float* out1 = (float*)d_out;                        // [50000,16]
    float* out2 = (float*)d_out + (size_t)N_NODES * 16; // [50000,64]

    char* ws = (char*)d_ws;
    float* bufA    = (float*)(ws);                    // 25,600,000
    float* bufB    = (float*)(ws + 25600000);         // 25,600,000
    float* bufC    = (float*)(ws + 51200000);         //  3,200,000
    int*   counts  = (int*)  (ws + 54400000);         //    200,064
    int*   row_ptr = (int*)  (ws + 54600064);         //    200,064
    int*   cursor  = (int*)  (ws + 54800128);         //    200,064
    int2*  pairs   = (int2*) (ws + 55000192);         //  6,400,000
    // total: 61,400,192 B

    unsigned short* W1frag = (unsigned short*)bufC;                    // 131,072 B
    unsigned short* W2frag = (unsigned short*)((char*)bufC + 131072);  //  16,384 B
    unsigned short* Wcfrag = (unsigned short*)((char*)bufC + 147456);  //  10,240 B

    // Buffer plan (no within-dispatch aliasing):
    //   sup1 [N,128]bf16 = bufA       (gemm1 w -> g128g2 r)
    //   sup2 [N, 64]bf16 = bufB       (g128g2 w -> g64g3 r)
    //   sup3 [N, 16]f32  = bufA       (g64g3 w, sup1 dead -> g16 r)
    unsigned short* sup1bf = (unsigned short*)bufA;
    unsigned short* sup2bf = (unsigned short*)bufB;
    float*          sup3   = bufA;

    const int EB  = (N_EDGES + 255) / 256;  // 3125
    const int GN  = N_NODES / 4;            // 12500 (wave-per-node gather16)
    const int GB  = N_NODES / 16;           // 3125 (16-node fused blocks)

    // --- prep + CSR build ---
    hipMemsetAsync(counts, 0, (size_t)N_NODES * 4, stream);
    convert_hist_kernel<<<308 + EB, 256, 0, stream>>>(
        W1, W2, We, W3, W1frag, W2frag, Wcfrag, esrc, counts);

    // 1. support1 = x @ W1 (MFMA, LDS-B)  ||  scan (1 hidden block)
    gemm1_scan_kernel<<<511, 256, 0, stream>>>(
        x, W1frag, sup1bf, counts, row_ptr, cursor);

    // CSR fill (needs cursor from scan)
    fill_kernel<<<EB, 256, 0, stream>>>(esrc, edst, edge_vals, cursor, pairs);

    // 2+3. sup2 = relu(gather(sup1)+b1) @ W2 (fused) -> bufB [N,64] bf16
    gather128_gemm2_kernel<<<GB, 256, 0, stream>>>(
        sup1bf, pairs, row_ptr, b1, W2frag, sup2bf);

    // 4+5+6. h2 = relu(gather(sup2)+b2); [out2|sup3] = h2 @ [We|W3] (fused)
    gather64_gemm3_kernel<<<GB, 256, 0, stream>>>(
        sup2bf, pairs, row_ptr, b2, Wcfrag, be, out2, sup3);

    // 7+8. out1 = log_softmax(gather(sup3) + b3)     -> d_out head
    gather16_lsm_kernel<<<GN, 256, 0, stream>>>(sup3, pairs, row_ptr, b3, out1);
}